// Round 4
// baseline (445.810 us; speedup 1.0000x reference)
//
#include <hip/hip_runtime.h>

typedef unsigned int   u32;
typedef unsigned short u16;
typedef __attribute__((ext_vector_type(8))) short bf16x8;
typedef __attribute__((ext_vector_type(4))) float f32x4;

// ---------- bf16 helpers ----------
__device__ __forceinline__ float bfs(u16 u) {
  union { u32 i; float f; } v; v.i = ((u32)u) << 16; return v.f;
}
__device__ __forceinline__ u16 f2bf(float f) {
  union { float f; u32 i; } v; v.f = f;
  u32 r = v.i + 0x7fffu + ((v.i >> 16) & 1u);   // RNE
  return (u16)(r >> 16);
}
__device__ __forceinline__ ushort4 f2bf4(float4 v) {
  ushort4 p; p.x = f2bf(v.x); p.y = f2bf(v.y); p.z = f2bf(v.z); p.w = f2bf(v.w);
  return p;
}

#define NBLK 512u

// Device-scope grid barrier. Safe because all 512 blocks are co-resident:
// LDS 47.1K -> 3 blocks/CU, launch_bounds(256,2) -> VGPR<=256 -> >=2 blocks/CU,
// grid=512=2x256CU. Counters zeroed by hipMemsetAsync before each launch.
__device__ __forceinline__ void gridbar(u32* cnt, int idx) {
  __threadfence();               // publish my writes device-wide
  __syncthreads();
  if (threadIdx.x == 0) {
    __hip_atomic_fetch_add(&cnt[idx], 1u, __ATOMIC_ACQ_REL, __HIP_MEMORY_SCOPE_AGENT);
    while (__hip_atomic_load(&cnt[idx], __ATOMIC_ACQUIRE, __HIP_MEMORY_SCOPE_AGENT) < NBLK) {}
  }
  __syncthreads();
  __threadfence();               // invalidate stale lines before reading others' data
}

// =================== single fused kernel (4 phases) =======================
// grid (tt=32, h=16), 256 threads (4 waves), 2 blocks/CU co-resident.
// Phase 1 (== old k_proj): projections, silu, logA scan, chunk-state G.
//   X^T/B/B^T/C/gate tiles stay in LDS for phase 3. Writes G, decArr, WoutB.
// Phase 2 (== old k_mid): block fb -> (bh = fb>>4, 256-elem slice); 16-step
//   prefix over chunks; writes Hpre (bf16).
// Phase 3 (== old k_ssm2): same (bh, chunk) as phase 1 -> tiles already in
//   LDS. Hpre fragments loaded global->reg directly. Writes Yg.
// Phase 4 (== old k_out): 64x64 out-tile per block (m-tile=tt, n-tile=h),
//   K=1024 loop staging Yg + WoutB through reused LDS.
__global__ __launch_bounds__(256, 2) void k_fused(
    const float* __restrict__ inp,
    const float* __restrict__ W_XBC,  const float* __restrict__ b_XBC,
    const float* __restrict__ W_gate, const float* __restrict__ b_gate,
    const float* __restrict__ W_logA, const float* __restrict__ b_logA,
    const float* __restrict__ Wout,   const float* __restrict__ bout,
    u32* __restrict__ bar,
    u16* __restrict__ WoutB, float* __restrict__ decArr,
    float* __restrict__ G, u16* __restrict__ HpreT,
    u16* __restrict__ Yg, float* __restrict__ out)
{
  const int tt = blockIdx.x, h = blockIdx.y;
  const int tid = threadIdx.x;
  const int w = tid >> 6, l = tid & 63, q = l >> 4, lr = l & 15;
  const int m0 = tt * 64;
  const int b = tt >> 4;
  const int bh = b * 16 + h;
  const int it = tt & 15;          // chunk index within batch

  __shared__ u16 Xt[64][72];       // input [t][c]; then B [t][n]; then Y-tile
  __shared__ u16 Wt[256][72];      // weights; then X^T/B^T|S/C/gate; then W-tile
  __shared__ float wl[64];         // W_logA row; then dec[16] in phase 2
  __shared__ float sg[64];
  __shared__ float ref_[64], cef[64];

  // ================= Phase 1: projections + scan + chunk state ============
  {
    int fid = h * 32 + tt;         // Wout f32->bf16, sliced over 512 blocks
    const float4* src = (const float4*)Wout + (size_t)fid * 512;
    ushort4* dst = (ushort4*)WoutB + (size_t)fid * 512;
    for (int i = tid; i < 512; i += 256) dst[i] = f2bf4(src[i]);
  }

  if (tid < 64) wl[tid] = W_logA[h * 64 + tid];
#pragma unroll
  for (int i = 0; i < 4; ++i) {
    int f = tid + 256 * i; int r = f >> 4, cq = f & 15;
    float4 xv = *(const float4*)(inp + (size_t)(m0 + r) * 1024 + h * 64 + 4 * cq);
    *(ushort4*)&Xt[r][4 * cq] = f2bf4(xv);
  }
#pragma unroll
  for (int i = 0; i < 16; ++i) {   // weights (inline f32->bf16)
    int f = tid + 256 * i; int r = f >> 4, cq = f & 15;
    const float* ws = (r < 192) ? (W_XBC + ((size_t)h * 192 + r) * 64)
                                : (W_gate + ((size_t)h * 64 + (r - 192)) * 64);
    *(ushort4*)&Wt[r][4 * cq] = f2bf4(*(const float4*)(ws + 4 * cq));
  }
  __syncthreads();

  {
    bf16x8 af[4][2];
#pragma unroll
    for (int rt = 0; rt < 4; ++rt) {
      af[rt][0] = *(const bf16x8*)&Xt[16 * rt + lr][q * 8];
      af[rt][1] = *(const bf16x8*)&Xt[16 * rt + lr][32 + q * 8];
    }

    f32x4 acc[4][4];
#pragma unroll
    for (int rt = 0; rt < 4; ++rt)
#pragma unroll
      for (int ct = 0; ct < 4; ++ct) acc[rt][ct] = (f32x4){0.f, 0.f, 0.f, 0.f};

#pragma unroll
    for (int ct = 0; ct < 4; ++ct) {
      bf16x8 b0 = *(const bf16x8*)&Wt[64 * w + 16 * ct + lr][q * 8];
      bf16x8 b1 = *(const bf16x8*)&Wt[64 * w + 16 * ct + lr][32 + q * 8];
#pragma unroll
      for (int rt = 0; rt < 4; ++rt) {
        acc[rt][ct] = __builtin_amdgcn_mfma_f32_16x16x32_bf16(af[rt][0], b0, acc[rt][ct], 0, 0, 0);
        acc[rt][ct] = __builtin_amdgcn_mfma_f32_16x16x32_bf16(af[rt][1], b1, acc[rt][ct], 0, 0, 0);
      }
    }

    // ---- local logA + 64-token inclusive scan (wave 0) ----
    if (tid < 64) {
      float a = b_logA[h];
#pragma unroll 16
      for (int k = 0; k < 64; ++k) a += bfs(Xt[tid][k]) * wl[k];
      float lv = a;
#pragma unroll
      for (int off = 1; off < 64; off <<= 1) {
        float n = __shfl_up(lv, off, 64);
        if (tid >= off) lv += n;
      }
      float L = __shfl(lv, 63, 64);
      sg[tid]   = __expf(L - lv);
      ref_[tid] = __expf(lv);      // stays in LDS for phase 3
      cef[tid]  = __expf(-lv);
      if (tid == 63) decArr[bh * 16 + it] = __expf(L);
    }

    // ---- bias + activation in registers ----
    if (w < 3) {
#pragma unroll
      for (int ct = 0; ct < 4; ++ct) {
        float bias = b_XBC[h * 192 + 64 * w + 16 * ct + lr];
#pragma unroll
        for (int rt = 0; rt < 4; ++rt)
#pragma unroll
          for (int r = 0; r < 4; ++r) {
            float s = acc[rt][ct][r] + bias;
            acc[rt][ct][r] = s / (1.f + __expf(-s));
          }
      }
    } else {
#pragma unroll
      for (int ct = 0; ct < 4; ++ct) {
        float bias = b_gate[h * 64 + 16 * ct + lr];
#pragma unroll
        for (int rt = 0; rt < 4; ++rt)
#pragma unroll
          for (int r = 0; r < 4; ++r) acc[rt][ct][r] += bias;
      }
    }
    __syncthreads();   // Wt frags + Xt (scan) consumed -> reuse as transpose bufs

    // ---- transpose into LDS (no global stores; tiles persist to phase 3) --
    // w==0: X^T [c][t] -> Wt rows 0..63
    // w==1: B^T [n][t] -> Wt rows 64..127 (chunk-state MFMA only)
    //       B   [t][n] -> Xt
    // w==2: C   [t][n] -> Wt rows 128..191
    // w==3: gate[t][c] -> Wt rows 192..255
#pragma unroll
    for (int ct = 0; ct < 4; ++ct)
#pragma unroll
      for (int rt = 0; rt < 4; ++rt)
#pragma unroll
        for (int r = 0; r < 4; ++r) {
          int t = 16 * rt + 4 * q + r, n = 16 * ct + lr;
          u16 v = f2bf(acc[rt][ct][r]);
          if (w == 0) {
            Wt[n][t] = v;
          } else if (w == 1) {
            Wt[64 + n][t] = v;
            Xt[t][n] = v;
          } else if (w == 2) {
            Wt[128 + t][n] = v;
          } else {
            Wt[192 + t][n] = v;
          }
        }
    __syncthreads();

    // ---- chunk state G[c][n] = sum_t X[t][c]*sg[t]*B[t][n] ----
    {
      bf16x8 a0r = *(const bf16x8*)&Wt[16 * w + lr][q * 8];
      bf16x8 a1r = *(const bf16x8*)&Wt[16 * w + lr][32 + q * 8];
      bf16x8 a0, a1;
#pragma unroll
      for (int jj = 0; jj < 8; ++jj) {
        a0[jj] = (short)f2bf(bfs((u16)a0r[jj]) * sg[q * 8 + jj]);
        a1[jj] = (short)f2bf(bfs((u16)a1r[jj]) * sg[32 + q * 8 + jj]);
      }
      f32x4 gacc[4];
#pragma unroll
      for (int nt = 0; nt < 4; ++nt) {
        gacc[nt] = (f32x4){0.f, 0.f, 0.f, 0.f};
        bf16x8 bb0 = *(const bf16x8*)&Wt[64 + 16 * nt + lr][q * 8];
        bf16x8 bb1 = *(const bf16x8*)&Wt[64 + 16 * nt + lr][32 + q * 8];
        gacc[nt] = __builtin_amdgcn_mfma_f32_16x16x32_bf16(a0, bb0, gacc[nt], 0, 0, 0);
        gacc[nt] = __builtin_amdgcn_mfma_f32_16x16x32_bf16(a1, bb1, gacc[nt], 0, 0, 0);
      }
      float* Gt = G + ((size_t)bh * 16 + it) * 4096;
#pragma unroll
      for (int nt = 0; nt < 4; ++nt)
#pragma unroll
        for (int r = 0; r < 4; ++r)
          Gt[(16 * w + 4 * q + r) * 64 + 16 * nt + lr] = gacc[nt][r];
    }
  }

  gridbar(bar, 0);

  // ================= Phase 2: state recurrence (remapped blocks) ==========
  {
    int fb = (h << 5) | tt;                 // 0..511
    int bh2 = fb >> 4;                      // 0..31
    int e = ((fb & 15) << 8) + tid;         // 0..4095, flat [c][n]
    if (tid < 16) wl[tid] = decArr[bh2 * 16 + tid];
    __syncthreads();
    const float* Gb = G + (size_t)bh2 * 16 * 4096 + e;
    u16* Hb = HpreT + (size_t)bh2 * 16 * 4096 + e;
    float gv[16];
#pragma unroll
    for (int j = 0; j < 16; ++j) gv[j] = Gb[(size_t)j * 4096];
    float hst = 0.f;
#pragma unroll
    for (int j = 0; j < 16; ++j) {
      Hb[(size_t)j * 4096] = f2bf(hst);
      hst = wl[j] * hst + gv[j];
    }
  }

  gridbar(bar, 1);

  // ================= Phase 3: diagonal quadratic + C·Hpre =================
  {
    const u16* Hb = HpreT + ((size_t)bh * 16 + it) * 4096;   // [c][n] bf16

    u16 (*Xts)[72] = (u16 (*)[72])&Wt[0];     // X^T [c][t]
    u16 (*Sts)[72] = (u16 (*)[72])&Wt[64];    // overwrite dead B^T
    u16 (*Cts)[72] = (u16 (*)[72])&Wt[128];   // C [t][n]
    u16 (*Gts)[72] = (u16 (*)[72])&Wt[192];   // gate [t][c]

    bf16x8 ca0 = *(const bf16x8*)&Cts[16 * w + lr][q * 8];
    bf16x8 ca1 = *(const bf16x8*)&Cts[16 * w + lr][32 + q * 8];

#pragma unroll
    for (int ct = 0; ct < 4; ++ct) {
      f32x4 s = (f32x4){0.f, 0.f, 0.f, 0.f};
      bf16x8 b0 = *(const bf16x8*)&Xt[16 * ct + lr][q * 8];    // B [t][n]
      bf16x8 b1 = *(const bf16x8*)&Xt[16 * ct + lr][32 + q * 8];
      s = __builtin_amdgcn_mfma_f32_16x16x32_bf16(ca0, b0, s, 0, 0, 0);
      s = __builtin_amdgcn_mfma_f32_16x16x32_bf16(ca1, b1, s, 0, 0, 0);
      int jl = 16 * ct + lr;
      float cj = cef[jl];
#pragma unroll
      for (int r = 0; r < 4; ++r) {
        int il = 16 * w + q * 4 + r;
        float v = (jl > il) ? 0.f : s[r] * ref_[il] * cj;
        Sts[il][jl] = f2bf(v);
      }
    }

    // Y = S·X_diag + diag(lexp)·(C·Hpre)  (same-wave Sts rows: no barrier)
    bf16x8 sa0 = *(const bf16x8*)&Sts[16 * w + lr][q * 8];
    bf16x8 sa1 = *(const bf16x8*)&Sts[16 * w + lr][32 + q * 8];
    f32x4 accd[4], acco[4];
#pragma unroll
    for (int ct = 0; ct < 4; ++ct) {
      accd[ct] = (f32x4){0.f, 0.f, 0.f, 0.f};
      acco[ct] = (f32x4){0.f, 0.f, 0.f, 0.f};
      bf16x8 x0 = *(const bf16x8*)&Xts[16 * ct + lr][q * 8];
      bf16x8 x1 = *(const bf16x8*)&Xts[16 * ct + lr][32 + q * 8];
      accd[ct] = __builtin_amdgcn_mfma_f32_16x16x32_bf16(sa0, x0, accd[ct], 0, 0, 0);
      accd[ct] = __builtin_amdgcn_mfma_f32_16x16x32_bf16(sa1, x1, accd[ct], 0, 0, 0);
      // Hpre fragments straight from global (16B-aligned bf16x8, L2-hot)
      bf16x8 h0 = *(const bf16x8*)(Hb + (size_t)(16 * ct + lr) * 64 + q * 8);
      bf16x8 h1 = *(const bf16x8*)(Hb + (size_t)(16 * ct + lr) * 64 + 32 + q * 8);
      acco[ct] = __builtin_amdgcn_mfma_f32_16x16x32_bf16(ca0, h0, acco[ct], 0, 0, 0);
      acco[ct] = __builtin_amdgcn_mfma_f32_16x16x32_bf16(ca1, h1, acco[ct], 0, 0, 0);
    }

    __syncthreads();   // all LDS reads done -> reuse Xts rows as Y [t][c]

#pragma unroll
    for (int ct = 0; ct < 4; ++ct) {
      int c = 16 * ct + lr;
#pragma unroll
      for (int r = 0; r < 4; ++r) {
        int il = 16 * w + q * 4 + r;
        float y = accd[ct][r] + ref_[il] * acco[ct][r];
        Xts[il][c] = f2bf(y);
      }
    }
    __syncthreads();

    // packed gated stores: Yg[b, m0+t, h*64 + c] = Y[t][c] * gate[t][c]
#pragma unroll
    for (int i = 0; i < 4; ++i) {
      int f = tid + 256 * i; int r = f >> 4, cq = f & 15;
      ushort4 yv = *(ushort4*)&Xts[r][4 * cq];
      ushort4 gv = *(ushort4*)&Gts[r][4 * cq];
      ushort4 o;
      o.x = f2bf(bfs(yv.x) * bfs(gv.x));
      o.y = f2bf(bfs(yv.y) * bfs(gv.y));
      o.z = f2bf(bfs(yv.z) * bfs(gv.z));
      o.w = f2bf(bfs(yv.w) * bfs(gv.w));
      *(ushort4*)(Yg + ((size_t)(m0 + r)) * 1024 + h * 64 + 4 * cq) = o;
    }
  }

  gridbar(bar, 2);

  // ================= Phase 4: out = Yg @ W_out^T + b_out ==================
  {
    const int d0 = h * 64;                  // n-tile; m-tile rows m0..m0+63
    u16 (*Yt)[72]  = Xt;                    // Y-tile  [64][72]
    u16 (*Wtt)[72] = (u16 (*)[72])&Wt[0];   // W-tile  [64][72]

    f32x4 oacc[4];
#pragma unroll
    for (int ct = 0; ct < 4; ++ct) oacc[ct] = (f32x4){0.f, 0.f, 0.f, 0.f};

    ushort4 py[4], pw[4];
#pragma unroll
    for (int i = 0; i < 4; ++i) {
      int f = tid + 256 * i; int r = f >> 4, cq = f & 15;
      py[i] = *(const ushort4*)(Yg + (size_t)(m0 + r) * 1024 + 4 * cq);
      pw[i] = *(const ushort4*)(WoutB + (size_t)(d0 + r) * 1024 + 4 * cq);
    }

    for (int kt = 0; kt < 16; ++kt) {
      __syncthreads();
#pragma unroll
      for (int i = 0; i < 4; ++i) {
        int f = tid + 256 * i; int r = f >> 4, cq = f & 15;
        *(ushort4*)&Yt[r][4 * cq]  = py[i];
        *(ushort4*)&Wtt[r][4 * cq] = pw[i];
      }
      __syncthreads();

      if (kt < 15) {
        int k1 = (kt + 1) * 64;
#pragma unroll
        for (int i = 0; i < 4; ++i) {
          int f = tid + 256 * i; int r = f >> 4, cq = f & 15;
          py[i] = *(const ushort4*)(Yg + (size_t)(m0 + r) * 1024 + k1 + 4 * cq);
          pw[i] = *(const ushort4*)(WoutB + (size_t)(d0 + r) * 1024 + k1 + 4 * cq);
        }
      }

      bf16x8 a0 = *(const bf16x8*)&Yt[16 * w + lr][q * 8];
      bf16x8 a1 = *(const bf16x8*)&Yt[16 * w + lr][32 + q * 8];
#pragma unroll
      for (int ct = 0; ct < 4; ++ct) {
        bf16x8 b0 = *(const bf16x8*)&Wtt[16 * ct + lr][q * 8];
        bf16x8 b1 = *(const bf16x8*)&Wtt[16 * ct + lr][32 + q * 8];
        oacc[ct] = __builtin_amdgcn_mfma_f32_16x16x32_bf16(a0, b0, oacc[ct], 0, 0, 0);
        oacc[ct] = __builtin_amdgcn_mfma_f32_16x16x32_bf16(a1, b1, oacc[ct], 0, 0, 0);
      }
    }

#pragma unroll
    for (int ct = 0; ct < 4; ++ct) {
      int d = d0 + 16 * ct + lr;
      float bo = bout[d];
#pragma unroll
      for (int r = 0; r < 4; ++r) {
        int m = m0 + 16 * w + q * 4 + r;
        out[(size_t)m * 1024 + d] = oacc[ct][r] + bo;
      }
    }
  }
}

// ---------------- host launcher ----------------
extern "C" void kernel_launch(void* const* d_in, const int* in_sizes, int n_in,
                              void* d_out, int out_size, void* d_ws, size_t ws_size,
                              hipStream_t stream)
{
  const float* inp   = (const float*)d_in[0];
  const float* WlogA = (const float*)d_in[1];
  const float* blogA = (const float*)d_in[2];
  const float* WXBC  = (const float*)d_in[3];
  const float* bXBC  = (const float*)d_in[4];
  const float* Wgate = (const float*)d_in[5];
  const float* bgate = (const float*)d_in[6];
  const float* Wout  = (const float*)d_in[7];
  const float* bout  = (const float*)d_in[8];
  float* out = (float*)d_out;

  u32*   bar   = (u32*)d_ws;                           // 3 counters (256 B pad)
  float* decA  = (float*)((char*)d_ws + 256);          // 512 f32
  float* G     = decA + 512;                           // 32*16*4096 f32 = 8 MiB
  u16*   WoutB = (u16*)(G + (size_t)32 * 16 * 4096);   // 1M u16 = 2 MiB
  u16*   HpreT = WoutB + (size_t)1024 * 1024;          // 2M u16 = 4 MiB
  u16*   Yg    = HpreT + (size_t)2 * 1024 * 1024;      // 2M u16 = 4 MiB

  hipMemsetAsync(bar, 0, 256, stream);                 // reset barrier counters

  k_fused<<<dim3(32, 16, 1), dim3(256, 1, 1), 0, stream>>>(
      inp, WXBC, bXBC, Wgate, bgate, WlogA, blogA, Wout, bout,
      bar, WoutB, decA, G, HpreT, Yg, out);
}

// Round 6
// 155.118 us; speedup vs baseline: 2.8740x; 2.8740x over previous
//
#include <hip/hip_runtime.h>

typedef unsigned int   u32;
typedef unsigned short u16;
typedef __attribute__((ext_vector_type(8))) short bf16x8;
typedef __attribute__((ext_vector_type(4))) float f32x4;

// ---------- bf16 helpers ----------
__device__ __forceinline__ float bfs(u16 u) {
  union { u32 i; float f; } v; v.i = ((u32)u) << 16; return v.f;
}
__device__ __forceinline__ u16 f2bf(float f) {
  union { float f; u32 i; } v; v.f = f;
  u32 r = v.i + 0x7fffu + ((v.i >> 16) & 1u);   // RNE
  return (u16)(r >> 16);
}
__device__ __forceinline__ ushort4 f2bf4(float4 v) {
  ushort4 p; p.x = f2bf(v.x); p.y = f2bf(v.y); p.z = f2bf(v.z); p.w = f2bf(v.w);
  return p;
}

// =================== Kernel A: proj + lookback-Hpre + ssm ==================
// grid (tt=32, h=16), 256 threads (4 waves). LDS 55K -> exactly 2 blocks/CU
// -> all 512 blocks co-resident -> per-bh flag chain cannot deadlock.
// Publish: G via agent-scope atomic f32 stores (reach coherence point, no
// fence), dec likewise, then release-store flag[bh*16+it].
// Consume: block (bh,it) waits flags j<it, reads G_j with NONTEMPORAL f32x4
// loads (bypass local L2 -> always fresh), runs h = dec_j*h + G_j in regs.
// No grid barrier, no __threadfence anywhere.
__global__ __launch_bounds__(256, 2) void k_main(
    const float* __restrict__ inp,
    const float* __restrict__ W_XBC,  const float* __restrict__ b_XBC,
    const float* __restrict__ W_gate, const float* __restrict__ b_gate,
    const float* __restrict__ W_logA, const float* __restrict__ b_logA,
    const float* __restrict__ Wout,   u16* __restrict__ WoutB,
    u32* __restrict__ flags, float* __restrict__ decArr,
    float* __restrict__ G, u16* __restrict__ Yg)
{
  const int tt = blockIdx.x, h = blockIdx.y;
  const int tid = threadIdx.x;
  const int w = tid >> 6, l = tid & 63, q = l >> 4, lr = l & 15;
  const int m0 = tt * 64;              // global token row (b*1024 + tl0)
  const int b = tt >> 4;
  const int bh = b * 16 + h;
  const int it = tt & 15;              // chunk index within batch

  __shared__ u16 Xt[64][72];           // input [t][c]; then B [t][n]
  __shared__ u16 Wt[256][72];          // weights; then X^T / B^T|S / C / gate
  __shared__ u16 Hl[64][72];           // Hpre [c][n] bf16 (lookback result)
  __shared__ float wl[64];             // W_logA row; then dec[j] in lookback
  __shared__ float sg[64];
  __shared__ float ref_[64], cef[64];

  // ---- Wout f32->bf16, sliced over 512 blocks ----
  {
    int fid = h * 32 + tt;
    const float4* src = (const float4*)Wout + (size_t)fid * 512;
    ushort4* dst = (ushort4*)WoutB + (size_t)fid * 512;
    for (int i = tid; i < 512; i += 256) dst[i] = f2bf4(src[i]);
  }

  if (tid < 64) wl[tid] = W_logA[h * 64 + tid];
#pragma unroll
  for (int i = 0; i < 4; ++i) {
    int f = tid + 256 * i; int r = f >> 4, cq = f & 15;
    float4 xv = *(const float4*)(inp + (size_t)(m0 + r) * 1024 + h * 64 + 4 * cq);
    *(ushort4*)&Xt[r][4 * cq] = f2bf4(xv);
  }
#pragma unroll
  for (int i = 0; i < 16; ++i) {       // weights (inline f32->bf16)
    int f = tid + 256 * i; int r = f >> 4, cq = f & 15;
    const float* ws = (r < 192) ? (W_XBC + ((size_t)h * 192 + r) * 64)
                                : (W_gate + ((size_t)h * 64 + (r - 192)) * 64);
    *(ushort4*)&Wt[r][4 * cq] = f2bf4(*(const float4*)(ws + 4 * cq));
  }
  __syncthreads();

  {
    bf16x8 af[4][2];
#pragma unroll
    for (int rt = 0; rt < 4; ++rt) {
      af[rt][0] = *(const bf16x8*)&Xt[16 * rt + lr][q * 8];
      af[rt][1] = *(const bf16x8*)&Xt[16 * rt + lr][32 + q * 8];
    }

    f32x4 acc[4][4];
#pragma unroll
    for (int rt = 0; rt < 4; ++rt)
#pragma unroll
      for (int ct = 0; ct < 4; ++ct) acc[rt][ct] = (f32x4){0.f, 0.f, 0.f, 0.f};

#pragma unroll
    for (int ct = 0; ct < 4; ++ct) {
      bf16x8 b0 = *(const bf16x8*)&Wt[64 * w + 16 * ct + lr][q * 8];
      bf16x8 b1 = *(const bf16x8*)&Wt[64 * w + 16 * ct + lr][32 + q * 8];
#pragma unroll
      for (int rt = 0; rt < 4; ++rt) {
        acc[rt][ct] = __builtin_amdgcn_mfma_f32_16x16x32_bf16(af[rt][0], b0, acc[rt][ct], 0, 0, 0);
        acc[rt][ct] = __builtin_amdgcn_mfma_f32_16x16x32_bf16(af[rt][1], b1, acc[rt][ct], 0, 0, 0);
      }
    }

    // ---- local logA + 64-token inclusive scan (wave 0) ----
    if (tid < 64) {
      float a = b_logA[h];
#pragma unroll 16
      for (int k = 0; k < 64; ++k) a += bfs(Xt[tid][k]) * wl[k];
      float lv = a;
#pragma unroll
      for (int off = 1; off < 64; off <<= 1) {
        float n = __shfl_up(lv, off, 64);
        if (tid >= off) lv += n;
      }
      float L = __shfl(lv, 63, 64);
      sg[tid]   = __expf(L - lv);
      ref_[tid] = __expf(lv);
      cef[tid]  = __expf(-lv);
      if (tid == 63)
        __hip_atomic_store(&decArr[bh * 16 + it], __expf(L),
                           __ATOMIC_RELAXED, __HIP_MEMORY_SCOPE_AGENT);
    }

    // ---- bias + activation in registers ----
    if (w < 3) {
#pragma unroll
      for (int ct = 0; ct < 4; ++ct) {
        float bias = b_XBC[h * 192 + 64 * w + 16 * ct + lr];
#pragma unroll
        for (int rt = 0; rt < 4; ++rt)
#pragma unroll
          for (int r = 0; r < 4; ++r) {
            float s = acc[rt][ct][r] + bias;
            acc[rt][ct][r] = s / (1.f + __expf(-s));
          }
      }
    } else {
#pragma unroll
      for (int ct = 0; ct < 4; ++ct) {
        float bias = b_gate[h * 64 + 16 * ct + lr];
#pragma unroll
        for (int rt = 0; rt < 4; ++rt)
#pragma unroll
          for (int r = 0; r < 4; ++r) acc[rt][ct][r] += bias;
      }
    }
    __syncthreads();   // Wt frags + Xt (scan) consumed

    // ---- transpose into LDS ----
    // w==0: X^T [c][t] -> Wt 0..63 ; w==1: B^T [n][t] -> Wt 64..127, B [t][n]
    // -> Xt ; w==2: C [t][n] -> Wt 128..191 ; w==3: gate [t][c] -> Wt 192..255
#pragma unroll
    for (int ct = 0; ct < 4; ++ct)
#pragma unroll
      for (int rt = 0; rt < 4; ++rt)
#pragma unroll
        for (int r = 0; r < 4; ++r) {
          int t = 16 * rt + 4 * q + r, n = 16 * ct + lr;
          u16 v = f2bf(acc[rt][ct][r]);
          if (w == 0) {
            Wt[n][t] = v;
          } else if (w == 1) {
            Wt[64 + n][t] = v;
            Xt[t][n] = v;
          } else if (w == 2) {
            Wt[128 + t][n] = v;
          } else {
            Wt[192 + t][n] = v;
          }
        }
    __syncthreads();

    // ---- chunk state G[c][n] = sum_t X[t][c]*sg[t]*B[t][n]; publish ----
    {
      bf16x8 a0r = *(const bf16x8*)&Wt[16 * w + lr][q * 8];
      bf16x8 a1r = *(const bf16x8*)&Wt[16 * w + lr][32 + q * 8];
      bf16x8 a0, a1;
#pragma unroll
      for (int jj = 0; jj < 8; ++jj) {
        a0[jj] = (short)f2bf(bfs((u16)a0r[jj]) * sg[q * 8 + jj]);
        a1[jj] = (short)f2bf(bfs((u16)a1r[jj]) * sg[32 + q * 8 + jj]);
      }
      f32x4 gacc[4];
#pragma unroll
      for (int nt = 0; nt < 4; ++nt) {
        gacc[nt] = (f32x4){0.f, 0.f, 0.f, 0.f};
        bf16x8 bb0 = *(const bf16x8*)&Wt[64 + 16 * nt + lr][q * 8];
        bf16x8 bb1 = *(const bf16x8*)&Wt[64 + 16 * nt + lr][32 + q * 8];
        gacc[nt] = __builtin_amdgcn_mfma_f32_16x16x32_bf16(a0, bb0, gacc[nt], 0, 0, 0);
        gacc[nt] = __builtin_amdgcn_mfma_f32_16x16x32_bf16(a1, bb1, gacc[nt], 0, 0, 0);
      }
      float* Gt = G + ((size_t)bh * 16 + it) * 4096;
#pragma unroll
      for (int nt = 0; nt < 4; ++nt)
#pragma unroll
        for (int r = 0; r < 4; ++r)
          __hip_atomic_store(&Gt[(16 * w + 4 * q + r) * 64 + 16 * nt + lr],
                             gacc[nt][r], __ATOMIC_RELAXED,
                             __HIP_MEMORY_SCOPE_AGENT);
    }
  }

  __syncthreads();   // drains vmcnt per wave -> all G/dec atomics completed
  if (tid == 0)
    __hip_atomic_store(&flags[bh * 16 + it], 1u,
                       __ATOMIC_RELEASE, __HIP_MEMORY_SCOPE_AGENT);

  // ================= decoupled lookback: Hpre for this chunk ==============
  // Thread owns 16 consecutive f32 of the flat [c][n] state: e = tid*16+k.
  float hreg[16];
#pragma unroll
  for (int k = 0; k < 16; ++k) hreg[k] = 0.f;

  if (it > 0) {
    if (tid < it) {
      while (__hip_atomic_load(&flags[bh * 16 + tid],
                               __ATOMIC_ACQUIRE, __HIP_MEMORY_SCOPE_AGENT) == 0u)
        __builtin_amdgcn_s_sleep(2);
      wl[tid] = __hip_atomic_load(&decArr[bh * 16 + tid],
                                  __ATOMIC_RELAXED, __HIP_MEMORY_SCOPE_AGENT);
    }
    __syncthreads();

    const float* Gb = G + (size_t)bh * 16 * 4096 + tid * 16;
    for (int j = 0; j < it; ++j) {
      const f32x4* Gj = (const f32x4*)(Gb + (size_t)j * 4096);
      f32x4 g0 = __builtin_nontemporal_load(Gj + 0);
      f32x4 g1 = __builtin_nontemporal_load(Gj + 1);
      f32x4 g2 = __builtin_nontemporal_load(Gj + 2);
      f32x4 g3 = __builtin_nontemporal_load(Gj + 3);
      float dj = wl[j];
      hreg[0]  = dj * hreg[0]  + g0[0]; hreg[1]  = dj * hreg[1]  + g0[1];
      hreg[2]  = dj * hreg[2]  + g0[2]; hreg[3]  = dj * hreg[3]  + g0[3];
      hreg[4]  = dj * hreg[4]  + g1[0]; hreg[5]  = dj * hreg[5]  + g1[1];
      hreg[6]  = dj * hreg[6]  + g1[2]; hreg[7]  = dj * hreg[7]  + g1[3];
      hreg[8]  = dj * hreg[8]  + g2[0]; hreg[9]  = dj * hreg[9]  + g2[1];
      hreg[10] = dj * hreg[10] + g2[2]; hreg[11] = dj * hreg[11] + g2[3];
      hreg[12] = dj * hreg[12] + g3[0]; hreg[13] = dj * hreg[13] + g3[1];
      hreg[14] = dj * hreg[14] + g3[2]; hreg[15] = dj * hreg[15] + g3[3];
    }
  }

  // Hl[c][n] <- bf16(hreg): thread covers row c=tid>>2, cols (tid&3)*16..+15
  {
    int c = tid >> 2, n0 = (tid & 3) * 16;
#pragma unroll
    for (int g4 = 0; g4 < 4; ++g4) {
      ushort4 hv;
      hv.x = f2bf(hreg[4 * g4 + 0]); hv.y = f2bf(hreg[4 * g4 + 1]);
      hv.z = f2bf(hreg[4 * g4 + 2]); hv.w = f2bf(hreg[4 * g4 + 3]);
      *(ushort4*)&Hl[c][n0 + 4 * g4] = hv;
    }
  }
  __syncthreads();

  // ================= ssm: diagonal quadratic + C·Hpre =====================
  {
    u16 (*Xts)[72] = (u16 (*)[72])&Wt[0];     // X^T [c][t]
    u16 (*Sts)[72] = (u16 (*)[72])&Wt[64];    // overwrite dead B^T
    u16 (*Cts)[72] = (u16 (*)[72])&Wt[128];   // C [t][n]
    u16 (*Gts)[72] = (u16 (*)[72])&Wt[192];   // gate [t][c]

    bf16x8 ca0 = *(const bf16x8*)&Cts[16 * w + lr][q * 8];
    bf16x8 ca1 = *(const bf16x8*)&Cts[16 * w + lr][32 + q * 8];

#pragma unroll
    for (int ct = 0; ct < 4; ++ct) {
      f32x4 s = (f32x4){0.f, 0.f, 0.f, 0.f};
      bf16x8 b0 = *(const bf16x8*)&Xt[16 * ct + lr][q * 8];    // B [t][n]
      bf16x8 b1 = *(const bf16x8*)&Xt[16 * ct + lr][32 + q * 8];
      s = __builtin_amdgcn_mfma_f32_16x16x32_bf16(ca0, b0, s, 0, 0, 0);
      s = __builtin_amdgcn_mfma_f32_16x16x32_bf16(ca1, b1, s, 0, 0, 0);
      int jl = 16 * ct + lr;
      float cj = cef[jl];
#pragma unroll
      for (int r = 0; r < 4; ++r) {
        int il = 16 * w + q * 4 + r;
        float v = (jl > il) ? 0.f : s[r] * ref_[il] * cj;
        Sts[il][jl] = f2bf(v);
      }
    }

    // Y = S·X_diag + diag(lexp)·(C·Hpre)  (same-wave Sts rows: no barrier)
    bf16x8 sa0 = *(const bf16x8*)&Sts[16 * w + lr][q * 8];
    bf16x8 sa1 = *(const bf16x8*)&Sts[16 * w + lr][32 + q * 8];
    f32x4 accd[4], acco[4];
#pragma unroll
    for (int ct = 0; ct < 4; ++ct) {
      accd[ct] = (f32x4){0.f, 0.f, 0.f, 0.f};
      acco[ct] = (f32x4){0.f, 0.f, 0.f, 0.f};
      bf16x8 x0 = *(const bf16x8*)&Xts[16 * ct + lr][q * 8];
      bf16x8 x1 = *(const bf16x8*)&Xts[16 * ct + lr][32 + q * 8];
      accd[ct] = __builtin_amdgcn_mfma_f32_16x16x32_bf16(sa0, x0, accd[ct], 0, 0, 0);
      accd[ct] = __builtin_amdgcn_mfma_f32_16x16x32_bf16(sa1, x1, accd[ct], 0, 0, 0);
      bf16x8 h0 = *(const bf16x8*)&Hl[16 * ct + lr][q * 8];
      bf16x8 h1 = *(const bf16x8*)&Hl[16 * ct + lr][32 + q * 8];
      acco[ct] = __builtin_amdgcn_mfma_f32_16x16x32_bf16(ca0, h0, acco[ct], 0, 0, 0);
      acco[ct] = __builtin_amdgcn_mfma_f32_16x16x32_bf16(ca1, h1, acco[ct], 0, 0, 0);
    }

    __syncthreads();   // all LDS reads done -> reuse Xts rows as Y [t][c]

#pragma unroll
    for (int ct = 0; ct < 4; ++ct) {
      int c = 16 * ct + lr;
#pragma unroll
      for (int r = 0; r < 4; ++r) {
        int il = 16 * w + q * 4 + r;
        float y = accd[ct][r] + ref_[il] * acco[ct][r];
        Xts[il][c] = f2bf(y);
      }
    }
    __syncthreads();

    // packed gated stores: Yg[m0+t][h*64+c] = Y[t][c] * gate[t][c]
#pragma unroll
    for (int i = 0; i < 4; ++i) {
      int f = tid + 256 * i; int r = f >> 4, cq = f & 15;
      ushort4 yv = *(ushort4*)&Xts[r][4 * cq];
      ushort4 gv = *(ushort4*)&Gts[r][4 * cq];
      ushort4 o;
      o.x = f2bf(bfs(yv.x) * bfs(gv.x));
      o.y = f2bf(bfs(yv.y) * bfs(gv.y));
      o.z = f2bf(bfs(yv.z) * bfs(gv.z));
      o.w = f2bf(bfs(yv.w) * bfs(gv.w));
      *(ushort4*)(Yg + (size_t)(m0 + r) * 1024 + h * 64 + 4 * cq) = o;
    }
  }
}

// ---------------- Kernel B: out = Yg @ W_out^T + b_out — MFMA, 8 waves -----
__global__ __launch_bounds__(512) void k_out(
    const u16* __restrict__ Yg, const u16* __restrict__ WoutB,
    const float* __restrict__ bout, float* __restrict__ out)
{
  int bm = blockIdx.x, bn = blockIdx.y;
  int tid = threadIdx.x;
  int w = tid >> 6, l = tid & 63, q = l >> 4, lr = l & 15;
  int m0 = bm * 128, d0 = bn * 64;

  __shared__ u16 Yt[128][72];
  __shared__ u16 Wt[64][72];

  f32x4 acc[4];
#pragma unroll
  for (int ct = 0; ct < 4; ++ct) acc[ct] = (f32x4){0.f, 0.f, 0.f, 0.f};

  ushort4 py[4], pw[2];
#pragma unroll
  for (int i = 0; i < 4; ++i) {
    int f = tid + 512 * i; int r = f >> 4, cq = f & 15;
    py[i] = *(const ushort4*)(Yg + (size_t)(m0 + r) * 1024 + 4 * cq);
  }
#pragma unroll
  for (int i = 0; i < 2; ++i) {
    int f = tid + 512 * i; int r = f >> 4, cq = f & 15;
    pw[i] = *(const ushort4*)(WoutB + (size_t)(d0 + r) * 1024 + 4 * cq);
  }

  for (int kt = 0; kt < 16; ++kt) {
    __syncthreads();
#pragma unroll
    for (int i = 0; i < 4; ++i) {
      int f = tid + 512 * i; int r = f >> 4, cq = f & 15;
      *(ushort4*)&Yt[r][4 * cq] = py[i];
    }
#pragma unroll
    for (int i = 0; i < 2; ++i) {
      int f = tid + 512 * i; int r = f >> 4, cq = f & 15;
      *(ushort4*)&Wt[r][4 * cq] = pw[i];
    }
    __syncthreads();

    if (kt < 15) {
      int k1 = (kt + 1) * 64;
#pragma unroll
      for (int i = 0; i < 4; ++i) {
        int f = tid + 512 * i; int r = f >> 4, cq = f & 15;
        py[i] = *(const ushort4*)(Yg + (size_t)(m0 + r) * 1024 + k1 + 4 * cq);
      }
#pragma unroll
      for (int i = 0; i < 2; ++i) {
        int f = tid + 512 * i; int r = f >> 4, cq = f & 15;
        pw[i] = *(const ushort4*)(WoutB + (size_t)(d0 + r) * 1024 + k1 + 4 * cq);
      }
    }

    bf16x8 a0 = *(const bf16x8*)&Yt[16 * w + lr][q * 8];
    bf16x8 a1 = *(const bf16x8*)&Yt[16 * w + lr][32 + q * 8];
#pragma unroll
    for (int ct = 0; ct < 4; ++ct) {
      bf16x8 b0 = *(const bf16x8*)&Wt[16 * ct + lr][q * 8];
      bf16x8 b1 = *(const bf16x8*)&Wt[16 * ct + lr][32 + q * 8];
      acc[ct] = __builtin_amdgcn_mfma_f32_16x16x32_bf16(a0, b0, acc[ct], 0, 0, 0);
      acc[ct] = __builtin_amdgcn_mfma_f32_16x16x32_bf16(a1, b1, acc[ct], 0, 0, 0);
    }
  }

#pragma unroll
  for (int ct = 0; ct < 4; ++ct) {
    int d = d0 + 16 * ct + lr;
    float bo = bout[d];
#pragma unroll
    for (int r = 0; r < 4; ++r) {
      int m = m0 + 16 * w + q * 4 + r;
      out[(size_t)m * 1024 + d] = acc[ct][r] + bo;
    }
  }
}

// ---------------- host launcher ----------------
extern "C" void kernel_launch(void* const* d_in, const int* in_sizes, int n_in,
                              void* d_out, int out_size, void* d_ws, size_t ws_size,
                              hipStream_t stream)
{
  const float* inp   = (const float*)d_in[0];
  const float* WlogA = (const float*)d_in[1];
  const float* blogA = (const float*)d_in[2];
  const float* WXBC  = (const float*)d_in[3];
  const float* bXBC  = (const float*)d_in[4];
  const float* Wgate = (const float*)d_in[5];
  const float* bgate = (const float*)d_in[6];
  const float* Wout  = (const float*)d_in[7];
  const float* bout  = (const float*)d_in[8];
  float* out = (float*)d_out;

  u32*   flags = (u32*)d_ws;                           // 512 u32 = 2 KiB
  float* decA  = (float*)((char*)d_ws + 2048);         // 512 f32 = 2 KiB
  float* G     = decA + 512;                           // 32*16*4096 f32 = 8 MiB
  u16*   WoutB = (u16*)(G + (size_t)32 * 16 * 4096);   // 1M u16 = 2 MiB
  u16*   Yg    = WoutB + (size_t)1024 * 1024;          // 2M u16 = 4 MiB

  (void)hipMemsetAsync(flags, 0, 2048, stream);        // reset chain flags

  k_main<<<dim3(32, 16, 1), dim3(256, 1, 1), 0, stream>>>(
      inp, WXBC, bXBC, Wgate, bgate, WlogA, blogA, Wout, WoutB,
      flags, decA, G, Yg);
  k_out<<<dim3(16, 16, 1), dim3(512, 1, 1), 0, stream>>>(Yg, WoutB, bout, out);
}

// Round 7
// 133.033 us; speedup vs baseline: 3.3511x; 1.1660x over previous
//
#include <hip/hip_runtime.h>

typedef unsigned int   u32;
typedef unsigned short u16;
typedef __attribute__((ext_vector_type(8))) short bf16x8;
typedef __attribute__((ext_vector_type(4))) float f32x4;

// ---------- bf16 helpers ----------
__device__ __forceinline__ float bfs(u16 u) {
  union { u32 i; float f; } v; v.i = ((u32)u) << 16; return v.f;
}
__device__ __forceinline__ u16 f2bf(float f) {
  union { float f; u32 i; } v; v.f = f;
  u32 r = v.i + 0x7fffu + ((v.i >> 16) & 1u);   // RNE
  return (u16)(r >> 16);
}
__device__ __forceinline__ ushort4 f2bf4(float4 v) {
  ushort4 p; p.x = f2bf(v.x); p.y = f2bf(v.y); p.z = f2bf(v.z); p.w = f2bf(v.w);
  return p;
}

// =================== Kernel A: proj + lookback-Hpre + ssm ==================
// grid (tt=32, h=16), 256 threads (4 waves). LDS 47104 B -> 3 blocks/CU
// (768 >= 512 co-resident -> per-bh flag chain cannot deadlock).
// Publish: G via agent-scope relaxed-atomic f32 stores (reach the coherence
// point), then release-store flag[bh*16+it].
// Consume: block (bh,it) waits flags j<it, reads G_j with PLAIN f32x4 loads
// (safe: lines only ever read after their flag within a launch; launch
// boundary invalidates L1/L2) -> L3/L2-served re-reads.
// Hpre lives in registers (hreg) until after the S-MFMA, then is stashed in
// Xt (B's tile, dead by then) -- no dedicated Hl tile, 3 blocks/CU.
__global__ __launch_bounds__(256, 2) void k_main(
    const float* __restrict__ inp,
    const float* __restrict__ W_XBC,  const float* __restrict__ b_XBC,
    const float* __restrict__ W_gate, const float* __restrict__ b_gate,
    const float* __restrict__ W_logA, const float* __restrict__ b_logA,
    u32* __restrict__ flags, float* __restrict__ decArr,
    float* __restrict__ G, u16* __restrict__ Yg)
{
  const int tt = blockIdx.x, h = blockIdx.y;
  const int tid = threadIdx.x;
  const int w = tid >> 6, l = tid & 63, q = l >> 4, lr = l & 15;
  const int m0 = tt * 64;              // global token row (b*1024 + tl0)
  const int b = tt >> 4;
  const int bh = b * 16 + h;
  const int it = tt & 15;              // chunk index within batch

  __shared__ u16 Xt[64][72];           // input [t][c]; B [t][n]; Hpre [c][n]
  __shared__ u16 Wt[256][72];          // weights; then X^T / B^T|S / C / gate
  __shared__ float wl[64];             // W_logA row; then dec[j] in lookback
  __shared__ float sg[64];
  __shared__ float ref_[64], cef[64];

  if (tid < 64) wl[tid] = W_logA[h * 64 + tid];
#pragma unroll
  for (int i = 0; i < 4; ++i) {
    int f = tid + 256 * i; int r = f >> 4, cq = f & 15;
    float4 xv = *(const float4*)(inp + (size_t)(m0 + r) * 1024 + h * 64 + 4 * cq);
    *(ushort4*)&Xt[r][4 * cq] = f2bf4(xv);
  }
#pragma unroll
  for (int i = 0; i < 16; ++i) {       // weights (inline f32->bf16)
    int f = tid + 256 * i; int r = f >> 4, cq = f & 15;
    const float* ws = (r < 192) ? (W_XBC + ((size_t)h * 192 + r) * 64)
                                : (W_gate + ((size_t)h * 64 + (r - 192)) * 64);
    *(ushort4*)&Wt[r][4 * cq] = f2bf4(*(const float4*)(ws + 4 * cq));
  }
  __syncthreads();

  {
    bf16x8 af[4][2];
#pragma unroll
    for (int rt = 0; rt < 4; ++rt) {
      af[rt][0] = *(const bf16x8*)&Xt[16 * rt + lr][q * 8];
      af[rt][1] = *(const bf16x8*)&Xt[16 * rt + lr][32 + q * 8];
    }

    f32x4 acc[4][4];
#pragma unroll
    for (int rt = 0; rt < 4; ++rt)
#pragma unroll
      for (int ct = 0; ct < 4; ++ct) acc[rt][ct] = (f32x4){0.f, 0.f, 0.f, 0.f};

#pragma unroll
    for (int ct = 0; ct < 4; ++ct) {
      bf16x8 b0 = *(const bf16x8*)&Wt[64 * w + 16 * ct + lr][q * 8];
      bf16x8 b1 = *(const bf16x8*)&Wt[64 * w + 16 * ct + lr][32 + q * 8];
#pragma unroll
      for (int rt = 0; rt < 4; ++rt) {
        acc[rt][ct] = __builtin_amdgcn_mfma_f32_16x16x32_bf16(af[rt][0], b0, acc[rt][ct], 0, 0, 0);
        acc[rt][ct] = __builtin_amdgcn_mfma_f32_16x16x32_bf16(af[rt][1], b1, acc[rt][ct], 0, 0, 0);
      }
    }

    // ---- local logA + 64-token inclusive scan (wave 0) ----
    if (tid < 64) {
      float a = b_logA[h];
#pragma unroll 16
      for (int k = 0; k < 64; ++k) a += bfs(Xt[tid][k]) * wl[k];
      float lv = a;
#pragma unroll
      for (int off = 1; off < 64; off <<= 1) {
        float n = __shfl_up(lv, off, 64);
        if (tid >= off) lv += n;
      }
      float L = __shfl(lv, 63, 64);
      sg[tid]   = __expf(L - lv);
      ref_[tid] = __expf(lv);
      cef[tid]  = __expf(-lv);
      if (tid == 63)
        __hip_atomic_store(&decArr[bh * 16 + it], __expf(L),
                           __ATOMIC_RELAXED, __HIP_MEMORY_SCOPE_AGENT);
    }

    // ---- bias + activation in registers ----
    if (w < 3) {
#pragma unroll
      for (int ct = 0; ct < 4; ++ct) {
        float bias = b_XBC[h * 192 + 64 * w + 16 * ct + lr];
#pragma unroll
        for (int rt = 0; rt < 4; ++rt)
#pragma unroll
          for (int r = 0; r < 4; ++r) {
            float s = acc[rt][ct][r] + bias;
            acc[rt][ct][r] = s / (1.f + __expf(-s));
          }
      }
    } else {
#pragma unroll
      for (int ct = 0; ct < 4; ++ct) {
        float bias = b_gate[h * 64 + 16 * ct + lr];
#pragma unroll
        for (int rt = 0; rt < 4; ++rt)
#pragma unroll
          for (int r = 0; r < 4; ++r) acc[rt][ct][r] += bias;
      }
    }
    __syncthreads();   // Wt frags + Xt (scan) consumed

    // ---- transpose into LDS ----
    // w==0: X^T [c][t] -> Wt 0..63 ; w==1: B^T [n][t] -> Wt 64..127, B [t][n]
    // -> Xt ; w==2: C [t][n] -> Wt 128..191 ; w==3: gate [t][c] -> Wt 192..255
#pragma unroll
    for (int ct = 0; ct < 4; ++ct)
#pragma unroll
      for (int rt = 0; rt < 4; ++rt)
#pragma unroll
        for (int r = 0; r < 4; ++r) {
          int t = 16 * rt + 4 * q + r, n = 16 * ct + lr;
          u16 v = f2bf(acc[rt][ct][r]);
          if (w == 0) {
            Wt[n][t] = v;
          } else if (w == 1) {
            Wt[64 + n][t] = v;
            Xt[t][n] = v;
          } else if (w == 2) {
            Wt[128 + t][n] = v;
          } else {
            Wt[192 + t][n] = v;
          }
        }
    __syncthreads();

    // ---- chunk state G[c][n] = sum_t X[t][c]*sg[t]*B[t][n]; publish ----
    {
      bf16x8 a0r = *(const bf16x8*)&Wt[16 * w + lr][q * 8];
      bf16x8 a1r = *(const bf16x8*)&Wt[16 * w + lr][32 + q * 8];
      bf16x8 a0, a1;
#pragma unroll
      for (int jj = 0; jj < 8; ++jj) {
        a0[jj] = (short)f2bf(bfs((u16)a0r[jj]) * sg[q * 8 + jj]);
        a1[jj] = (short)f2bf(bfs((u16)a1r[jj]) * sg[32 + q * 8 + jj]);
      }
      f32x4 gacc[4];
#pragma unroll
      for (int nt = 0; nt < 4; ++nt) {
        gacc[nt] = (f32x4){0.f, 0.f, 0.f, 0.f};
        bf16x8 bb0 = *(const bf16x8*)&Wt[64 + 16 * nt + lr][q * 8];
        bf16x8 bb1 = *(const bf16x8*)&Wt[64 + 16 * nt + lr][32 + q * 8];
        gacc[nt] = __builtin_amdgcn_mfma_f32_16x16x32_bf16(a0, bb0, gacc[nt], 0, 0, 0);
        gacc[nt] = __builtin_amdgcn_mfma_f32_16x16x32_bf16(a1, bb1, gacc[nt], 0, 0, 0);
      }
      float* Gt = G + ((size_t)bh * 16 + it) * 4096;
#pragma unroll
      for (int nt = 0; nt < 4; ++nt)
#pragma unroll
        for (int r = 0; r < 4; ++r)
          __hip_atomic_store(&Gt[(16 * w + 4 * q + r) * 64 + 16 * nt + lr],
                             gacc[nt][r], __ATOMIC_RELAXED,
                             __HIP_MEMORY_SCOPE_AGENT);
    }
  }

  __syncthreads();   // drains vmcnt per wave -> all G/dec atomics completed
  if (tid == 0)
    __hip_atomic_store(&flags[bh * 16 + it], 1u,
                       __ATOMIC_RELEASE, __HIP_MEMORY_SCOPE_AGENT);

  // ================= decoupled lookback: Hpre for this chunk ==============
  // Thread owns 16 consecutive f32 of the flat [c][n] state: e = tid*16+k.
  float hreg[16];
#pragma unroll
  for (int k = 0; k < 16; ++k) hreg[k] = 0.f;

  if (it > 0) {
    if (tid < it) {
      while (__hip_atomic_load(&flags[bh * 16 + tid],
                               __ATOMIC_ACQUIRE, __HIP_MEMORY_SCOPE_AGENT) == 0u)
        __builtin_amdgcn_s_sleep(2);
      wl[tid] = __hip_atomic_load(&decArr[bh * 16 + tid],
                                  __ATOMIC_RELAXED, __HIP_MEMORY_SCOPE_AGENT);
    }
    __syncthreads();

    const float* Gb = G + (size_t)bh * 16 * 4096 + tid * 16;
    for (int j = 0; j < it; ++j) {
      const f32x4* Gj = (const f32x4*)(Gb + (size_t)j * 4096);
      f32x4 g0 = Gj[0];
      f32x4 g1 = Gj[1];
      f32x4 g2 = Gj[2];
      f32x4 g3 = Gj[3];
      float dj = wl[j];
      hreg[0]  = dj * hreg[0]  + g0[0]; hreg[1]  = dj * hreg[1]  + g0[1];
      hreg[2]  = dj * hreg[2]  + g0[2]; hreg[3]  = dj * hreg[3]  + g0[3];
      hreg[4]  = dj * hreg[4]  + g1[0]; hreg[5]  = dj * hreg[5]  + g1[1];
      hreg[6]  = dj * hreg[6]  + g1[2]; hreg[7]  = dj * hreg[7]  + g1[3];
      hreg[8]  = dj * hreg[8]  + g2[0]; hreg[9]  = dj * hreg[9]  + g2[1];
      hreg[10] = dj * hreg[10] + g2[2]; hreg[11] = dj * hreg[11] + g2[3];
      hreg[12] = dj * hreg[12] + g3[0]; hreg[13] = dj * hreg[13] + g3[1];
      hreg[14] = dj * hreg[14] + g3[2]; hreg[15] = dj * hreg[15] + g3[3];
    }
  }

  // ================= ssm: diagonal quadratic + C·Hpre =====================
  {
    u16 (*Xts)[72] = (u16 (*)[72])&Wt[0];     // X^T [c][t]
    u16 (*Sts)[72] = (u16 (*)[72])&Wt[64];    // overwrite dead B^T
    u16 (*Cts)[72] = (u16 (*)[72])&Wt[128];   // C [t][n]
    u16 (*Gts)[72] = (u16 (*)[72])&Wt[192];   // gate [t][c]

    bf16x8 ca0 = *(const bf16x8*)&Cts[16 * w + lr][q * 8];
    bf16x8 ca1 = *(const bf16x8*)&Cts[16 * w + lr][32 + q * 8];

    // S = tril(ref_i * (C·B^T)_ij * cef_j)  -- B read from Xt (last use)
#pragma unroll
    for (int ct = 0; ct < 4; ++ct) {
      f32x4 s = (f32x4){0.f, 0.f, 0.f, 0.f};
      bf16x8 b0 = *(const bf16x8*)&Xt[16 * ct + lr][q * 8];    // B [t][n]
      bf16x8 b1 = *(const bf16x8*)&Xt[16 * ct + lr][32 + q * 8];
      s = __builtin_amdgcn_mfma_f32_16x16x32_bf16(ca0, b0, s, 0, 0, 0);
      s = __builtin_amdgcn_mfma_f32_16x16x32_bf16(ca1, b1, s, 0, 0, 0);
      int jl = 16 * ct + lr;
      float cj = cef[jl];
#pragma unroll
      for (int r = 0; r < 4; ++r) {
        int il = 16 * w + q * 4 + r;
        float v = (jl > il) ? 0.f : s[r] * ref_[il] * cj;
        Sts[il][jl] = f2bf(v);
      }
    }
    __syncthreads();   // Xt (B) fully consumed -> stash Hpre into Xt

    // Hpre [c][n] <- bf16(hreg): thread covers row c=tid>>2, cols (tid&3)*16..
    {
      int c = tid >> 2, n0 = (tid & 3) * 16;
#pragma unroll
      for (int g4 = 0; g4 < 4; ++g4) {
        ushort4 hv;
        hv.x = f2bf(hreg[4 * g4 + 0]); hv.y = f2bf(hreg[4 * g4 + 1]);
        hv.z = f2bf(hreg[4 * g4 + 2]); hv.w = f2bf(hreg[4 * g4 + 3]);
        *(ushort4*)&Xt[c][n0 + 4 * g4] = hv;
      }
    }
    __syncthreads();

    // Y = S·X_diag + diag(lexp)·(C·Hpre)
    bf16x8 sa0 = *(const bf16x8*)&Sts[16 * w + lr][q * 8];
    bf16x8 sa1 = *(const bf16x8*)&Sts[16 * w + lr][32 + q * 8];
    f32x4 accd[4], acco[4];
#pragma unroll
    for (int ct = 0; ct < 4; ++ct) {
      accd[ct] = (f32x4){0.f, 0.f, 0.f, 0.f};
      acco[ct] = (f32x4){0.f, 0.f, 0.f, 0.f};
      bf16x8 x0 = *(const bf16x8*)&Xts[16 * ct + lr][q * 8];
      bf16x8 x1 = *(const bf16x8*)&Xts[16 * ct + lr][32 + q * 8];
      accd[ct] = __builtin_amdgcn_mfma_f32_16x16x32_bf16(sa0, x0, accd[ct], 0, 0, 0);
      accd[ct] = __builtin_amdgcn_mfma_f32_16x16x32_bf16(sa1, x1, accd[ct], 0, 0, 0);
      bf16x8 h0 = *(const bf16x8*)&Xt[16 * ct + lr][q * 8];    // Hpre [c][n]
      bf16x8 h1 = *(const bf16x8*)&Xt[16 * ct + lr][32 + q * 8];
      acco[ct] = __builtin_amdgcn_mfma_f32_16x16x32_bf16(ca0, h0, acco[ct], 0, 0, 0);
      acco[ct] = __builtin_amdgcn_mfma_f32_16x16x32_bf16(ca1, h1, acco[ct], 0, 0, 0);
    }

    __syncthreads();   // all LDS reads done -> reuse Xts rows as Y [t][c]

#pragma unroll
    for (int ct = 0; ct < 4; ++ct) {
      int c = 16 * ct + lr;
#pragma unroll
      for (int r = 0; r < 4; ++r) {
        int il = 16 * w + q * 4 + r;
        float y = accd[ct][r] + ref_[il] * acco[ct][r];
        Xts[il][c] = f2bf(y);
      }
    }
    __syncthreads();

    // packed gated stores: Yg[m0+t][h*64+c] = Y[t][c] * gate[t][c]
#pragma unroll
    for (int i = 0; i < 4; ++i) {
      int f = tid + 256 * i; int r = f >> 4, cq = f & 15;
      ushort4 yv = *(ushort4*)&Xts[r][4 * cq];
      ushort4 gv = *(ushort4*)&Gts[r][4 * cq];
      ushort4 o;
      o.x = f2bf(bfs(yv.x) * bfs(gv.x));
      o.y = f2bf(bfs(yv.y) * bfs(gv.y));
      o.z = f2bf(bfs(yv.z) * bfs(gv.z));
      o.w = f2bf(bfs(yv.w) * bfs(gv.w));
      *(ushort4*)(Yg + (size_t)(m0 + r) * 1024 + h * 64 + 4 * cq) = o;
    }
  }
}

// ---------------- Kernel B: out = Yg @ W_out^T + b_out — MFMA, 8 waves -----
// Converts W_out f32->bf16 in registers during staging (no WoutB pre-pass).
__global__ __launch_bounds__(512) void k_out(
    const u16* __restrict__ Yg, const float* __restrict__ Wout,
    const float* __restrict__ bout, float* __restrict__ out)
{
  int bm = blockIdx.x, bn = blockIdx.y;
  int tid = threadIdx.x;
  int w = tid >> 6, l = tid & 63, q = l >> 4, lr = l & 15;
  int m0 = bm * 128, d0 = bn * 64;

  __shared__ u16 Yt[128][72];
  __shared__ u16 Wt[64][72];

  f32x4 acc[4];
#pragma unroll
  for (int ct = 0; ct < 4; ++ct) acc[ct] = (f32x4){0.f, 0.f, 0.f, 0.f};

  ushort4 py[4];
  float4 pwf[2];
#pragma unroll
  for (int i = 0; i < 4; ++i) {
    int f = tid + 512 * i; int r = f >> 4, cq = f & 15;
    py[i] = *(const ushort4*)(Yg + (size_t)(m0 + r) * 1024 + 4 * cq);
  }
#pragma unroll
  for (int i = 0; i < 2; ++i) {
    int f = tid + 512 * i; int r = f >> 4, cq = f & 15;
    pwf[i] = *(const float4*)(Wout + (size_t)(d0 + r) * 1024 + 4 * cq);
  }

  for (int kt = 0; kt < 16; ++kt) {
    __syncthreads();
#pragma unroll
    for (int i = 0; i < 4; ++i) {
      int f = tid + 512 * i; int r = f >> 4, cq = f & 15;
      *(ushort4*)&Yt[r][4 * cq] = py[i];
    }
#pragma unroll
    for (int i = 0; i < 2; ++i) {
      int f = tid + 512 * i; int r = f >> 4, cq = f & 15;
      *(ushort4*)&Wt[r][4 * cq] = f2bf4(pwf[i]);
    }
    __syncthreads();

    if (kt < 15) {
      int k1 = (kt + 1) * 64;
#pragma unroll
      for (int i = 0; i < 4; ++i) {
        int f = tid + 512 * i; int r = f >> 4, cq = f & 15;
        py[i] = *(const ushort4*)(Yg + (size_t)(m0 + r) * 1024 + k1 + 4 * cq);
      }
#pragma unroll
      for (int i = 0; i < 2; ++i) {
        int f = tid + 512 * i; int r = f >> 4, cq = f & 15;
        pwf[i] = *(const float4*)(Wout + (size_t)(d0 + r) * 1024 + k1 + 4 * cq);
      }
    }

    bf16x8 a0 = *(const bf16x8*)&Yt[16 * w + lr][q * 8];
    bf16x8 a1 = *(const bf16x8*)&Yt[16 * w + lr][32 + q * 8];
#pragma unroll
    for (int ct = 0; ct < 4; ++ct) {
      bf16x8 b0 = *(const bf16x8*)&Wt[16 * ct + lr][q * 8];
      bf16x8 b1 = *(const bf16x8*)&Wt[16 * ct + lr][32 + q * 8];
      acc[ct] = __builtin_amdgcn_mfma_f32_16x16x32_bf16(a0, b0, acc[ct], 0, 0, 0);
      acc[ct] = __builtin_amdgcn_mfma_f32_16x16x32_bf16(a1, b1, acc[ct], 0, 0, 0);
    }
  }

#pragma unroll
  for (int ct = 0; ct < 4; ++ct) {
    int d = d0 + 16 * ct + lr;
    float bo = bout[d];
#pragma unroll
    for (int r = 0; r < 4; ++r) {
      int m = m0 + 16 * w + q * 4 + r;
      out[(size_t)m * 1024 + d] = acc[ct][r] + bo;
    }
  }
}

// ---------------- host launcher ----------------
extern "C" void kernel_launch(void* const* d_in, const int* in_sizes, int n_in,
                              void* d_out, int out_size, void* d_ws, size_t ws_size,
                              hipStream_t stream)
{
  const float* inp   = (const float*)d_in[0];
  const float* WlogA = (const float*)d_in[1];
  const float* blogA = (const float*)d_in[2];
  const float* WXBC  = (const float*)d_in[3];
  const float* bXBC  = (const float*)d_in[4];
  const float* Wgate = (const float*)d_in[5];
  const float* bgate = (const float*)d_in[6];
  const float* Wout  = (const float*)d_in[7];
  const float* bout  = (const float*)d_in[8];
  float* out = (float*)d_out;

  u32*   flags = (u32*)d_ws;                           // 512 u32 = 2 KiB
  float* decA  = (float*)((char*)d_ws + 2048);         // 512 f32 = 2 KiB
  float* G     = decA + 512;                           // 32*16*4096 f32 = 8 MiB
  u16*   Yg    = (u16*)(G + (size_t)32 * 16 * 4096);   // 2M u16 = 4 MiB

  (void)hipMemsetAsync(flags, 0, 2048, stream);        // reset chain flags

  k_main<<<dim3(32, 16, 1), dim3(256, 1, 1), 0, stream>>>(
      inp, WXBC, bXBC, Wgate, bgate, WlogA, blogA,
      flags, decA, G, Yg);
  k_out<<<dim3(16, 16, 1), dim3(512, 1, 1), 0, stream>>>(Yg, Wout, bout, out);
}